// Round 9
// baseline (19.695 us; speedup 1.0000x reference)
//
#include <hip/hip_runtime.h>
#include <hip/hip_bf16.h>

// Problem dims (fixed): n=128, d=256, ic=16, oc=16, r=10
// x:   [n, d, ic, r]  = 5,242,880 f32
// w:   [d, ic, oc, r] =   655,360 f32   (r innermost)
// out: [n, d, oc, r]  = 5,242,880 f32
//
// out[n,d,oc,r] = log( sum_ic exp(x)*exp(w) ) - log( sum_ic exp(w) )
// |x|,|w| <~ 5.5 so unnormalized exp is safe; LDS operands bf16
// (measured absmax 0.0156 << 7.4e-2 threshold).
//
// v9 = v6 structure (32n chunk, 4n x 4oc x r tile, ALL 320 threads active
// in compute -> 2 LDS reads/ic per 16 outputs, half of v8's per-output
// LDS cost) + v5-proven f32 res epilogue (RSP=164; v6's res bug was its
// 64-float row stride, fixed here). LDS instrs/thread ~84 vs v8's ~116.

#define EROW 36    // exs row stride (bf16)
#define WROW 20    // wes row stride (bf16)
#define RSP  164   // res row stride (f32); 656B rows: 16B-aligned, 4-bank shift

__global__ __launch_bounds__(320, 5) void fused_lse_kernel(const float* __restrict__ x,
                                                           const float* __restrict__ w,
                                                           float* __restrict__ out) {
    __shared__ __align__(16) __hip_bfloat16 exs[160 * EROW];  // 11.25 KB
    __shared__ __align__(16) __hip_bfloat16 wes[160 * WROW];  //  6.25 KB
    __shared__ float lcs[160];                                //  0.64 KB
    __shared__ __align__(16) float res[32 * RSP];             // 21    KB

    const int tid    = threadIdx.x;
    const int d      = blockIdx.x & 255;
    const int n_base = (blockIdx.x >> 8) << 5;   // 4 supers of 32 n

    // ---- stage exp(w[d]) -> wes[ic*10+r][oc] (bf16, per-elem transpose) ----
    {
        const float4* wg = reinterpret_cast<const float4*>(w + d * 2560);
        float4 a = wg[tid * 2];
        float4 b = wg[tid * 2 + 1];
        float vals[8] = {a.x, a.y, a.z, a.w, b.x, b.y, b.z, b.w};
        const int base = tid * 8;
#pragma unroll
        for (int k = 0; k < 8; ++k) {
            const int off = base + k;
            const int ic  = off / 160;
            const int ocr = off - ic * 160;
            const int oc  = ocr / 10;
            const int r   = ocr - oc * 10;
            wes[(ic * 10 + r) * WROW + oc] = __float2bfloat16(__expf(vals[k]));
        }
    }

    // ---- stage exp(x) -> exs[r*16+ic][colswz(n)] (bf16) ---------------------
    // col = ((n_l>>2) ^ (seg&7))*4 + (n_l&3); reader: seg == icr>>4
    {
        const int n_l = tid / 10;                        // 0..31
        const int seg = tid % 10;                        // 0..9
        const float* xg = x + ((n_base + n_l) * 256 + d) * 160 + seg * 16;
        float4 v0 = *reinterpret_cast<const float4*>(xg);
        float4 v1 = *reinterpret_cast<const float4*>(xg + 4);
        float4 v2 = *reinterpret_cast<const float4*>(xg + 8);
        float4 v3 = *reinterpret_cast<const float4*>(xg + 12);
        float vals[16] = {v0.x, v0.y, v0.z, v0.w, v1.x, v1.y, v1.z, v1.w,
                          v2.x, v2.y, v2.z, v2.w, v3.x, v3.y, v3.z, v3.w};
        const int cbase = (((n_l >> 2) ^ (seg & 7)) << 2) + (n_l & 3);
#pragma unroll
        for (int k = 0; k < 16; ++k) {
            const int icr = seg * 16 + k;                // = ic*10 + r
            const int ic  = icr / 10;
            const int r   = icr - ic * 10;
            exs[(r * 16 + ic) * EROW + cbase] = __float2bfloat16(__expf(vals[k]));
        }
    }
    __syncthreads();

    // ---- lcs[oc*10+r] = log( sum_ic wes[icr][oc] ) --------------------------
    if (tid < 160) {
        const int oc = tid / 10, rr = tid - (tid / 10) * 10;
        float s = 0.f;
#pragma unroll
        for (int ic = 0; ic < 16; ++ic)
            s += __bfloat162float(wes[(ic * 10 + rr) * WROW + oc]);
        lcs[tid] = __logf(s);
    }

    // ---- compute: thread = (r, g, oc4), tile 4n x 4oc at fixed r ------------
    const int r   = tid >> 5;          // 0..9
    const int g   = (tid & 31) >> 2;   // 0..7  -> n0 = 4g
    const int oc4 = tid & 3;           // 0..3  -> oc0 = 4*oc4
    const int n0  = g << 2;
    const int oc0 = oc4 << 2;

    float acc[4][4] = {{0.f}};
#pragma unroll
    for (int ic = 0; ic < 16; ++ic) {
        const int row = r * 16 + ic;
        const int icr = ic * 10 + r;
        const int sgw = (icr >> 4) & 7;
        const uint2 eu = *reinterpret_cast<const uint2*>(&exs[row * EROW + ((g ^ sgw) << 2)]);
        const uint2 wu = *reinterpret_cast<const uint2*>(&wes[icr * WROW + (oc4 << 2)]);
        const float e0 = __uint_as_float(eu.x << 16);
        const float e1 = __uint_as_float(eu.x & 0xFFFF0000u);
        const float e2 = __uint_as_float(eu.y << 16);
        const float e3 = __uint_as_float(eu.y & 0xFFFF0000u);
        const float w0 = __uint_as_float(wu.x << 16);
        const float w1 = __uint_as_float(wu.x & 0xFFFF0000u);
        const float w2 = __uint_as_float(wu.y << 16);
        const float w3 = __uint_as_float(wu.y & 0xFFFF0000u);
        acc[0][0] = fmaf(e0, w0, acc[0][0]);
        acc[0][1] = fmaf(e0, w1, acc[0][1]);
        acc[0][2] = fmaf(e0, w2, acc[0][2]);
        acc[0][3] = fmaf(e0, w3, acc[0][3]);
        acc[1][0] = fmaf(e1, w0, acc[1][0]);
        acc[1][1] = fmaf(e1, w1, acc[1][1]);
        acc[1][2] = fmaf(e1, w2, acc[1][2]);
        acc[1][3] = fmaf(e1, w3, acc[1][3]);
        acc[2][0] = fmaf(e2, w0, acc[2][0]);
        acc[2][1] = fmaf(e2, w1, acc[2][1]);
        acc[2][2] = fmaf(e2, w2, acc[2][2]);
        acc[2][3] = fmaf(e2, w3, acc[2][3]);
        acc[3][0] = fmaf(e3, w0, acc[3][0]);
        acc[3][1] = fmaf(e3, w1, acc[3][1]);
        acc[3][2] = fmaf(e3, w2, acc[3][2]);
        acc[3][3] = fmaf(e3, w3, acc[3][3]);
    }
    __syncthreads();   // lcs complete; exs/wes reads done

    // ---- epilogue: finish in regs, scatter to res (v5-proven layout) --------
    {
        float lc[4];
#pragma unroll
        for (int j = 0; j < 4; ++j) lc[j] = lcs[(oc0 + j) * 10 + r];
#pragma unroll
        for (int i = 0; i < 4; ++i)
#pragma unroll
            for (int j = 0; j < 4; ++j)
                res[(n0 + i) * RSP + (oc0 + j) * 10 + r] = __logf(acc[i][j]) - lc[j];
    }
    __syncthreads();

    // ---- coalesced store: 16 floats/thread (lanes 0-9 = one 640B row) ------
    {
        const int n2  = tid / 10;                        // 0..31
        const int sg2 = tid % 10;                        // 0..9
        const float* rp = res + n2 * RSP + sg2 * 16;
        float4 o0 = *reinterpret_cast<const float4*>(rp);
        float4 o1 = *reinterpret_cast<const float4*>(rp + 4);
        float4 o2 = *reinterpret_cast<const float4*>(rp + 8);
        float4 o3 = *reinterpret_cast<const float4*>(rp + 12);
        float* og = out + ((n_base + n2) * 256 + d) * 160 + sg2 * 16;
        *reinterpret_cast<float4*>(og)      = o0;
        *reinterpret_cast<float4*>(og + 4)  = o1;
        *reinterpret_cast<float4*>(og + 8)  = o2;
        *reinterpret_cast<float4*>(og + 12) = o3;
    }
}

extern "C" void kernel_launch(void* const* d_in, const int* in_sizes, int n_in,
                              void* d_out, int out_size, void* d_ws, size_t ws_size,
                              hipStream_t stream) {
    const float* x = (const float*)d_in[0];
    const float* w = (const float*)d_in[1];
    float* out = (float*)d_out;

    // grid = (4 n-supers) * (256 d); block covers 32 n x 1 d, all (oc, r)
    fused_lse_kernel<<<1024, 320, 0, stream>>>(x, w, out);
}

// Round 10
// 19.060 us; speedup vs baseline: 1.0333x; 1.0333x over previous
//
#include <hip/hip_runtime.h>
#include <hip/hip_bf16.h>

// Problem dims (fixed): n=128, d=256, ic=16, oc=16, r=10
// x:   [n, d, ic, r]  = 5,242,880 f32
// w:   [d, ic, oc, r] =   655,360 f32   (r innermost)
// out: [n, d, oc, r]  = 5,242,880 f32
//
// out[n,d,oc,r] = log( sum_ic exp(x)*exp(w) ) - log( sum_ic exp(w) )
// LDS operands bf16 (measured absmax 0.0156 << 7.4e-2 threshold).
//
// v10: block = (d, 64n) as FOUR pipelined 16n chunks (v8 had two -> mostly
// fill/drain). 512 blocks x 320 threads, double-buffered exs/res, 2
// barriers/chunk steady state; every steady phase pairs memory with compute
// (store_prev || compute_cur ; stage_next || epilogue_cur). x-loads issued
// 1-2 phases before their stage. All inner components verbatim from v8.

#define EROW 20    // exs row stride (bf16)
#define WROW 20    // wes row stride (bf16)
#define RSP  164   // res row stride (f32)

using bf16 = __hip_bfloat16;

__device__ __forceinline__ void stage_x_chunk(bf16* exs, const float4& a,
                                              const float4& b, int seg8, int colw) {
    float vals[8] = {a.x, a.y, a.z, a.w, b.x, b.y, b.z, b.w};
#pragma unroll
    for (int k = 0; k < 8; ++k)
        exs[(seg8 * 8 + k) * EROW + colw] = __float2bfloat16(__expf(vals[k]));
}

__device__ __forceinline__ void compute_chunk(const bf16* exs, const bf16* wes,
                                              int r, int ng, int oc4, float acc[2][4]) {
#pragma unroll
    for (int i = 0; i < 2; ++i)
#pragma unroll
        for (int j = 0; j < 4; ++j) acc[i][j] = 0.f;
#pragma unroll
    for (int ic = 0; ic < 16; ++ic) {
        const int icr = ic * 10 + r;
        const int cb = (((ng >> 1) ^ ((icr >> 3) & 3)) << 2) + ((ng & 1) << 1);
        const unsigned eu = *reinterpret_cast<const unsigned*>(&exs[icr * EROW + cb]);
        const uint2 wu = *reinterpret_cast<const uint2*>(&wes[icr * WROW + (oc4 << 2)]);
        const float e0 = __uint_as_float(eu << 16);
        const float e1 = __uint_as_float(eu & 0xFFFF0000u);
        const float w0 = __uint_as_float(wu.x << 16);
        const float w1 = __uint_as_float(wu.x & 0xFFFF0000u);
        const float w2 = __uint_as_float(wu.y << 16);
        const float w3 = __uint_as_float(wu.y & 0xFFFF0000u);
        acc[0][0] = fmaf(e0, w0, acc[0][0]);
        acc[0][1] = fmaf(e0, w1, acc[0][1]);
        acc[0][2] = fmaf(e0, w2, acc[0][2]);
        acc[0][3] = fmaf(e0, w3, acc[0][3]);
        acc[1][0] = fmaf(e1, w0, acc[1][0]);
        acc[1][1] = fmaf(e1, w1, acc[1][1]);
        acc[1][2] = fmaf(e1, w2, acc[1][2]);
        acc[1][3] = fmaf(e1, w3, acc[1][3]);
    }
}

__device__ __forceinline__ void epilogue_chunk(float* res, const float* lcs,
                                               int r, int ng, int oc4, float acc[2][4]) {
#pragma unroll
    for (int j = 0; j < 4; ++j) {
        const int ocr = ((oc4 << 2) + j) * 10 + r;
        const float lcj = lcs[ocr];
#pragma unroll
        for (int i = 0; i < 2; ++i) {
            const int n = (ng << 1) + i;                 // block-local row 0..15
            const int q = (ocr >> 2) ^ (n & 7);          // quad swizzle (bijective)
            res[n * RSP + (q << 2) + (ocr & 3)] = __logf(acc[i][j]) - lcj;
        }
    }
}

__device__ __forceinline__ void store_chunk(const float* res, float* __restrict__ out,
                                            int nbase, int d, int n_l, int seg8) {
    const int f = n_l & 7;
    const float4 v0 = *reinterpret_cast<const float4*>(&res[n_l * RSP + ((((seg8 << 1) | 0) ^ f) << 2)]);
    const float4 v1 = *reinterpret_cast<const float4*>(&res[n_l * RSP + ((((seg8 << 1) | 1) ^ f) << 2)]);
    float* og = out + ((nbase + n_l) * 256 + d) * 160 + seg8 * 8;
    *reinterpret_cast<float4*>(og)     = v0;
    *reinterpret_cast<float4*>(og + 4) = v1;
}

__global__ __launch_bounds__(320, 2) void fused_lse_kernel(const float* __restrict__ x,
                                                           const float* __restrict__ w,
                                                           float* __restrict__ out) {
    __shared__ __align__(16) bf16 wes[160 * WROW];    //  6.25 KB
    __shared__ __align__(16) bf16 exsA[160 * EROW];   //  6.25 KB
    __shared__ __align__(16) bf16 exsB[160 * EROW];   //  6.25 KB
    __shared__ float lcs[160];                        //  0.64 KB
    __shared__ __align__(16) float resA[16 * RSP];    // 10.5  KB
    __shared__ __align__(16) float resB[16 * RSP];    // 10.5  KB

    const int tid = threadIdx.x;
    const int d   = blockIdx.x & 255;
    const int nb  = (blockIdx.x >> 8) << 6;           // 0 or 64

    const int n_l  = tid / 20;    // 0..15
    const int seg8 = tid % 20;    // 0..19
    const int colw = (((n_l >> 2) ^ (seg8 & 3)) << 2) + (n_l & 3);

    const float* xbase = x + ((nb + n_l) * 256 + d) * 160 + seg8 * 8;
    const int CS = 16 * 256 * 160;                    // chunk stride (floats)

    // ---- P1: issue w, x0, x1; stage w -> wes; stage x0 -> A -----------------
    const float4* wg = reinterpret_cast<const float4*>(w + d * 2560);
    const float4 wa = wg[tid * 2];
    const float4 wb = wg[tid * 2 + 1];
    const float4 a0 = *reinterpret_cast<const float4*>(xbase);
    const float4 b0 = *reinterpret_cast<const float4*>(xbase + 4);
    const float4 a1 = *reinterpret_cast<const float4*>(xbase + CS);
    const float4 b1 = *reinterpret_cast<const float4*>(xbase + CS + 4);
    {
        float vals[8] = {wa.x, wa.y, wa.z, wa.w, wb.x, wb.y, wb.z, wb.w};
        const int base = tid * 8;
#pragma unroll
        for (int k = 0; k < 8; ++k) {
            const int off = base + k;
            const int ic  = off / 160;
            const int ocr = off - ic * 160;
            const int oc  = ocr / 10;
            const int r   = ocr - oc * 10;
            wes[(ic * 10 + r) * WROW + oc] = __float2bfloat16(__expf(vals[k]));
        }
    }
    stage_x_chunk(exsA, a0, b0, seg8, colw);
    __syncthreads();

    // ---- P2: issue x2; lcs; compute c0(A); stage x1 -> B --------------------
    const float4 a2 = *reinterpret_cast<const float4*>(xbase + 2 * CS);
    const float4 b2 = *reinterpret_cast<const float4*>(xbase + 2 * CS + 4);
    if (tid < 160) {
        const int oc = tid / 10, rr = tid - (tid / 10) * 10;
        float s = 0.f;
#pragma unroll
        for (int ic = 0; ic < 16; ++ic)
            s += __bfloat162float(wes[(ic * 10 + rr) * WROW + oc]);
        lcs[tid] = __logf(s);
    }
    const int r   = tid >> 5;        // 0..9
    const int ng  = (tid >> 2) & 7;  // 0..7
    const int oc4 = tid & 3;         // 0..3
    float accX[2][4], accY[2][4];
    compute_chunk(exsA, wes, r, ng, oc4, accX);
    stage_x_chunk(exsB, a1, b1, seg8, colw);
    __syncthreads();

    // ---- P3: issue x3; stage x2 -> A; epilogue c0 -> resA -------------------
    const float4 a3 = *reinterpret_cast<const float4*>(xbase + 3 * CS);
    const float4 b3 = *reinterpret_cast<const float4*>(xbase + 3 * CS + 4);
    stage_x_chunk(exsA, a2, b2, seg8, colw);
    epilogue_chunk(resA, lcs, r, ng, oc4, accX);
    __syncthreads();

    // ---- P4: store c0(resA); compute c1(B) ----------------------------------
    store_chunk(resA, out, nb + 0, d, n_l, seg8);
    compute_chunk(exsB, wes, r, ng, oc4, accY);
    __syncthreads();

    // ---- P5: stage x3 -> B; epilogue c1 -> resB -----------------------------
    stage_x_chunk(exsB, a3, b3, seg8, colw);
    epilogue_chunk(resB, lcs, r, ng, oc4, accY);
    __syncthreads();

    // ---- P6: store c1(resB); compute c2(A) ----------------------------------
    store_chunk(resB, out, nb + 16, d, n_l, seg8);
    compute_chunk(exsA, wes, r, ng, oc4, accX);
    __syncthreads();

    // ---- P7: epilogue c2 -> resA --------------------------------------------
    epilogue_chunk(resA, lcs, r, ng, oc4, accX);
    __syncthreads();

    // ---- P8: store c2(resA); compute c3(B) ----------------------------------
    store_chunk(resA, out, nb + 32, d, n_l, seg8);
    compute_chunk(exsB, wes, r, ng, oc4, accY);
    __syncthreads();

    // ---- P9: epilogue c3 -> resB --------------------------------------------
    epilogue_chunk(resB, lcs, r, ng, oc4, accY);
    __syncthreads();

    // ---- P10: store c3(resB) ------------------------------------------------
    store_chunk(resB, out, nb + 48, d, n_l, seg8);
}

extern "C" void kernel_launch(void* const* d_in, const int* in_sizes, int n_in,
                              void* d_out, int out_size, void* d_ws, size_t ws_size,
                              hipStream_t stream) {
    const float* x = (const float*)d_in[0];
    const float* w = (const float*)d_in[1];
    float* out = (float*)d_out;

    // grid = (2 n-supers of 64) * (256 d); block = 64 n x 1 d as 4 chunks
    fused_lse_kernel<<<512, 320, 0, stream>>>(x, w, out);
}